// Round 1
// baseline (1127.584 us; speedup 1.0000x reference)
//
#include <hip/hip_runtime.h>
#include <hip/hip_bf16.h>

// Problem constants
#define Bsz 128
#define Ssz 256
#define Lsz 200
#define Dsz 768
#define POS_DIM 50
#define REDUC 400
#define HID 150
#define TAGS 5
#define POL 4
#define NROW (Bsz * Lsz)          // 25600
#define FIN (Dsz + POS_DIM)       // 818

// ---------------------------------------------------------------------------
// prep: concat the 4 hidden weight mats into Wh[600,400], biases into bh[600],
// extract biaffine bias column bias_bi[600] = W_bi[:,150]
// ---------------------------------------------------------------------------
__global__ void prep_kernel(const float* __restrict__ W_ap, const float* __restrict__ W_op,
                            const float* __restrict__ W_ap2, const float* __restrict__ W_op2,
                            const float* __restrict__ b_ap, const float* __restrict__ b_op,
                            const float* __restrict__ b_ap2, const float* __restrict__ b_op2,
                            const float* __restrict__ W_bi,
                            float* __restrict__ Wh, float* __restrict__ bh,
                            float* __restrict__ bias_bi)
{
    int i = blockIdx.x * blockDim.x + threadIdx.x;
    if (i < 600 * 400) {
        int r = i / 400, c = i % 400;
        const float* src = (r < 150) ? W_ap : (r < 300) ? W_op : (r < 450) ? W_ap2 : W_op2;
        Wh[i] = src[(r % 150) * 400 + c];
    }
    if (i < 600) {
        const float* bs = (i < 150) ? b_ap : (i < 300) ? b_op : (i < 450) ? b_ap2 : b_op2;
        bh[i] = bs[i % 150];
        bias_bi[i] = W_bi[i * 151 + 150];
    }
}

// ---------------------------------------------------------------------------
// pool: h[row, 0:50] = embed_table[postag[row]], h[row, 50:818] = mean of
// bert_vectors over subword span [start,end] (inclusive)
// ---------------------------------------------------------------------------
__global__ void pool_kernel(const float* __restrict__ bert,      // [B,S,D]
                            const int* __restrict__ positions,   // [B,L,2]
                            const int* __restrict__ postag,      // [B,L]
                            const float* __restrict__ embed,     // [60,50]
                            float* __restrict__ h)               // [NROW, FIN]
{
    int row = blockIdx.x;                 // b*L + l
    int b = row / Lsz;
    int st = positions[row * 2 + 0];
    int en = positions[row * 2 + 1];
    int tag = postag[row];
    int span = en - st + 1;               // >= 1 by construction
    float inv = 1.0f / (float)span;
    const float* base = bert + ((long)b * Ssz + st) * Dsz;
    for (int f = threadIdx.x; f < FIN; f += blockDim.x) {
        float v;
        if (f < POS_DIM) {
            v = embed[tag * POS_DIM + f];
        } else {
            int d = f - POS_DIM;
            float s = 0.0f;
            for (int i = 0; i < span; ++i) s += base[i * Dsz + d];
            v = s * inv;
        }
        h[(long)row * FIN + f] = v;
    }
}

// ---------------------------------------------------------------------------
// Generic tiled fp32 GEMM: C[m,n] = sum_k A[m,k] * Bt[n,k] (+bias[n]) (+relu)
// Batched via blockIdx.z with element strides sAb/sBb/sCb.
// BM=BN=64, BK=16, 256 threads, 4x4 microtile. Full bounds guards.
// ---------------------------------------------------------------------------
#define BM 64
#define BN 64
#define BK 16

__global__ __launch_bounds__(256) void gemm_bt(
    const float* __restrict__ A, long long sAb, int lda,
    const float* __restrict__ Bt, long long sBb, int ldb,
    const float* __restrict__ bias,
    float* __restrict__ C, long long sCb, int ldc,
    int M, int N, int K, int relu)
{
    __shared__ float As[BK][BM + 4];
    __shared__ float Bs[BK][BN + 4];

    int bz = blockIdx.z;
    A += (long long)bz * sAb;
    Bt += (long long)bz * sBb;
    C += (long long)bz * sCb;

    int row0 = blockIdx.y * BM;
    int col0 = blockIdx.x * BN;
    int tid = threadIdx.x;
    int tx = tid % 16;       // 0..15 -> 4 cols each
    int ty = tid / 16;       // 0..15 -> 4 rows each
    int lk = tid % 16;       // loader k index
    int lm0 = tid / 16;      // loader row base (16 rows/pass, 4 passes)

    float acc[4][4] = {};

    for (int k0 = 0; k0 < K; k0 += BK) {
        int gk = k0 + lk;
        bool kok = (gk < K);
#pragma unroll
        for (int p = 0; p < 4; ++p) {
            int m = lm0 + p * 16;
            int gm = row0 + m;
            As[lk][m] = (kok && gm < M) ? A[(long)gm * lda + gk] : 0.0f;
        }
#pragma unroll
        for (int p = 0; p < 4; ++p) {
            int n = lm0 + p * 16;
            int gn = col0 + n;
            Bs[lk][n] = (kok && gn < N) ? Bt[(long)gn * ldb + gk] : 0.0f;
        }
        __syncthreads();
#pragma unroll
        for (int kk = 0; kk < BK; ++kk) {
            float a[4], bv[4];
#pragma unroll
            for (int i = 0; i < 4; ++i) a[i] = As[kk][ty * 4 + i];
#pragma unroll
            for (int j = 0; j < 4; ++j) bv[j] = Bs[kk][tx * 4 + j];
#pragma unroll
            for (int i = 0; i < 4; ++i)
#pragma unroll
                for (int j = 0; j < 4; ++j)
                    acc[i][j] += a[i] * bv[j];
        }
        __syncthreads();
    }

#pragma unroll
    for (int i = 0; i < 4; ++i) {
        int gm = row0 + ty * 4 + i;
        if (gm >= M) continue;
#pragma unroll
        for (int j = 0; j < 4; ++j) {
            int gn = col0 + tx * 4 + j;
            if (gn >= N) continue;
            float v = acc[i][j] + (bias ? bias[gn] : 0.0f);
            if (relu) v = fmaxf(v, 0.0f);
            C[(long)gm * ldc + gn] = v;
        }
    }
}

// ---------------------------------------------------------------------------
// tags: ap_out[row,t] = b_aptag[t] + ap_rep[row,:]·W_aptag[t,:]  (K=150)
//       op_out[row,t] likewise from op_rep = hidden[:,150:300]
// One wave (64 lanes) per row, 4 rows per 256-thread block.
// ---------------------------------------------------------------------------
__global__ __launch_bounds__(256) void tags_kernel(
    const float* __restrict__ hidden,   // [NROW, 600]
    const float* __restrict__ W_aptag, const float* __restrict__ b_aptag,
    const float* __restrict__ W_optag, const float* __restrict__ b_optag,
    float* __restrict__ out_ap, float* __restrict__ out_op)
{
    int wave = threadIdx.x / 64;
    int lane = threadIdx.x % 64;
    int row = blockIdx.x * 4 + wave;
    if (row >= NROW) return;
    const float* hr = hidden + (long)row * 600;

#pragma unroll
    for (int which = 0; which < 2; ++which) {
        const float* rep = hr + which * 150;
        const float* W = which ? W_optag : W_aptag;
        const float* bb = which ? b_optag : b_aptag;
        float* out = which ? out_op : out_ap;
        float v0 = rep[lane];
        float v1 = rep[64 + lane];
        float v2 = (lane < 22) ? rep[128 + lane] : 0.0f;
#pragma unroll
        for (int t = 0; t < TAGS; ++t) {
            const float* w = W + t * 150;
            float p = v0 * w[lane] + v1 * w[64 + lane] +
                      ((lane < 22) ? v2 * w[128 + lane] : 0.0f);
#pragma unroll
            for (int off = 32; off > 0; off >>= 1) p += __shfl_down(p, off);
            if (lane == 0) out[row * TAGS + t] = p + bb[t];
        }
    }
}

// ---------------------------------------------------------------------------
extern "C" void kernel_launch(void* const* d_in, const int* in_sizes, int n_in,
                              void* d_out, int out_size, void* d_ws, size_t ws_size,
                              hipStream_t stream)
{
    const float* bert      = (const float*)d_in[0];
    const int*   positions = (const int*)d_in[1];
    const int*   postag    = (const int*)d_in[2];
    const float* embed     = (const float*)d_in[3];
    const float* W_reduc   = (const float*)d_in[4];
    const float* b_reduc   = (const float*)d_in[5];
    const float* W_ap      = (const float*)d_in[6];
    const float* b_ap      = (const float*)d_in[7];
    const float* W_op      = (const float*)d_in[8];
    const float* b_op      = (const float*)d_in[9];
    const float* W_ap2     = (const float*)d_in[10];
    const float* b_ap2     = (const float*)d_in[11];
    const float* W_op2     = (const float*)d_in[12];
    const float* b_op2     = (const float*)d_in[13];
    const float* W_aptag   = (const float*)d_in[14];
    const float* b_aptag   = (const float*)d_in[15];
    const float* W_optag   = (const float*)d_in[16];
    const float* b_optag   = (const float*)d_in[17];
    const float* W_bi      = (const float*)d_in[18];

    float* out = (float*)d_out;
    float* out_ap  = out;                 // [25600, 5]
    float* out_op  = out + NROW * TAGS;   // [25600, 5]
    float* out_tri = out + 2 * NROW * TAGS; // [B, 200, 800]

    // Workspace layout (floats). affine aliases h (h dead after reduc GEMM).
    float* f = (float*)d_ws;
    float* h       = f;                               // 25600*818 = 20,940,800
    float* reduc   = h + (long)NROW * FIN;            // 25600*400 = 10,240,000
    float* hidden  = reduc + (long)NROW * REDUC;      // 25600*600 = 15,360,000
    float* Wh      = hidden + (long)NROW * 600;       // 240,000
    float* bh      = Wh + 600 * 400;                  // 600
    float* bias_bi = bh + 600;                        // 600
    float* affine  = h;                               // alias: 25600*600 <= h size

    // 1. prep weights
    prep_kernel<<<(600 * 400 + 255) / 256, 256, 0, stream>>>(
        W_ap, W_op, W_ap2, W_op2, b_ap, b_op, b_ap2, b_op2, W_bi, Wh, bh, bias_bi);

    // 2. pool + embed + concat -> h [25600, 818]
    pool_kernel<<<NROW, 256, 0, stream>>>(bert, positions, postag, embed, h);

    // 3. reduc = h @ W_reduc^T + b_reduc   [25600,400], K=818
    {
        dim3 g((REDUC + BN - 1) / BN, NROW / BM, 1);
        gemm_bt<<<g, 256, 0, stream>>>(h, 0, FIN, W_reduc, 0, FIN, b_reduc,
                                       reduc, 0, REDUC, NROW, REDUC, FIN, 0);
    }

    // 4. hidden = relu(reduc @ Wh^T + bh)  [25600,600], K=400
    {
        dim3 g((600 + BN - 1) / BN, NROW / BM, 1);
        gemm_bt<<<g, 256, 0, stream>>>(reduc, 0, REDUC, Wh, 0, REDUC, bh,
                                       hidden, 0, 600, NROW, 600, REDUC, 1);
    }

    // 5. tag heads -> out_ap, out_op
    tags_kernel<<<NROW / 4, 256, 0, stream>>>(hidden, W_aptag, b_aptag,
                                              W_optag, b_optag, out_ap, out_op);

    // 6. affine = ap_node @ W_bi[:, :150]^T + W_bi[:,150]   [25600,600], K=150
    //    ap_node = hidden cols [300,450)
    {
        dim3 g((600 + BN - 1) / BN, NROW / BM, 1);
        gemm_bt<<<g, 256, 0, stream>>>(hidden + 300, 0, 600, W_bi, 0, 151, bias_bi,
                                       affine, 0, 600, NROW, 600, HID, 0);
    }

    // 7. tri (batched over B): out_tri[b][l2][k] = op_node[b,l2,:]·affine_b[k,:]
    //    op_node = hidden cols [450,600); affine_b is [800,150] contiguous
    {
        dim3 g((800 + BN - 1) / BN, (Lsz + BM - 1) / BM, Bsz);
        gemm_bt<<<g, 256, 0, stream>>>(hidden + 450, (long long)Lsz * 600, 600,
                                       affine, (long long)Lsz * POL * HID, HID,
                                       nullptr,
                                       out_tri, (long long)Lsz * Lsz * POL, Lsz * POL,
                                       Lsz, Lsz * POL, HID, 0);
    }
}

// Round 2
// 513.490 us; speedup vs baseline: 2.1959x; 2.1959x over previous
//
#include <hip/hip_runtime.h>
#include <hip/hip_bf16.h>

// Problem constants
#define Bsz 128
#define Ssz 256
#define Lsz 200
#define Dsz 768
#define POS_DIM 50
#define TAGS 5
#define NROW 25600          // B*L
#define FIN 818             // D + POS_DIM
#define KH 832              // FIN padded to mult of 32 (and 8)
#define KR 416              // REDUC=400 padded
#define KD 160              // HID=150 padded

typedef __attribute__((ext_vector_type(8))) short short8;
typedef __attribute__((ext_vector_type(4))) float floatx4;

__device__ __forceinline__ short f2bf(float v) {
    __hip_bfloat16 h = __float2bfloat16(v);
    short s; __builtin_memcpy(&s, &h, 2); return s;
}
__device__ __forceinline__ float bf2f(short s) {
    __hip_bfloat16 h; __builtin_memcpy(&h, &s, 2);
    return __bfloat162float(h);
}

__device__ __forceinline__ void gload16(const short* g, short* l) {
    __builtin_amdgcn_global_load_lds(
        (const __attribute__((address_space(1))) void*)g,
        (__attribute__((address_space(3))) void*)l, 16, 0, 0);
}

// ---------------------------------------------------------------------------
// prep: build zero-padded bf16 weight copies + padded fp32 biases
//   Wr_bf  [512][832] <- W_reduc [400][818]
//   Wh_bf  [640][416] <- {W_ap,W_op,W_ap2,W_op2} [150][400] stacked
//   Wbi_bf [640][160] <- W_bi[:, :150]  ([600][151])
//   br_pad[416], bh_pad[640], bbi_pad[640] (= W_bi[:,150])
// ---------------------------------------------------------------------------
__global__ void prep_kernel(const float* __restrict__ W_reduc,
                            const float* __restrict__ W_ap, const float* __restrict__ W_op,
                            const float* __restrict__ W_ap2, const float* __restrict__ W_op2,
                            const float* __restrict__ W_bi,
                            const float* __restrict__ b_reduc,
                            const float* __restrict__ b_ap, const float* __restrict__ b_op,
                            const float* __restrict__ b_ap2, const float* __restrict__ b_op2,
                            short* __restrict__ Wr_bf, short* __restrict__ Wh_bf,
                            short* __restrict__ Wbi_bf,
                            float* __restrict__ br_pad, float* __restrict__ bh_pad,
                            float* __restrict__ bbi_pad)
{
    int i = blockIdx.x * blockDim.x + threadIdx.x;
    if (i < 512 * KH) {
        int r = i / KH, c = i % KH;
        Wr_bf[i] = (r < 400 && c < FIN) ? f2bf(W_reduc[r * FIN + c]) : (short)0;
    }
    if (i < 640 * KR) {
        int r = i / KR, c = i % KR;
        float v = 0.0f;
        if (r < 600 && c < 400) {
            const float* src = (r < 150) ? W_ap : (r < 300) ? W_op : (r < 450) ? W_ap2 : W_op2;
            v = src[(r % 150) * 400 + c];
        }
        Wh_bf[i] = f2bf(v);
    }
    if (i < 640 * KD) {
        int r = i / KD, c = i % KD;
        Wbi_bf[i] = (r < 600 && c < 150) ? f2bf(W_bi[r * 151 + c]) : (short)0;
    }
    if (i < KR) br_pad[i] = (i < 400) ? b_reduc[i] : 0.0f;
    if (i < 640) {
        float v = 0.0f;
        if (i < 600) {
            const float* bs = (i < 150) ? b_ap : (i < 300) ? b_op : (i < 450) ? b_ap2 : b_op2;
            v = bs[i % 150];
        }
        bh_pad[i] = v;
        bbi_pad[i] = (i < 600) ? W_bi[i * 151 + 150] : 0.0f;
    }
}

// ---------------------------------------------------------------------------
// pool: h_bf[row][0:50]=embed[tag], [50:818]=span mean of bert, [818:832]=0
// ---------------------------------------------------------------------------
__global__ void pool_kernel(const float* __restrict__ bert,
                            const int* __restrict__ positions,
                            const int* __restrict__ postag,
                            const float* __restrict__ embed,
                            short* __restrict__ h_bf)
{
    int row = blockIdx.x;
    int b = row / Lsz;
    int st = positions[row * 2 + 0];
    int en = positions[row * 2 + 1];
    int tag = postag[row];
    int span = en - st + 1;
    float inv = 1.0f / (float)span;
    const float* base = bert + ((long)b * Ssz + st) * Dsz;
    short* hr = h_bf + (long)row * KH;
    for (int f = threadIdx.x; f < KH; f += blockDim.x) {
        float v = 0.0f;
        if (f < POS_DIM) {
            v = embed[tag * POS_DIM + f];
        } else if (f < FIN) {
            int d = f - POS_DIM;
            float s = 0.0f;
            for (int i = 0; i < span; ++i) s += base[i * Dsz + d];
            v = s * inv;
        }
        hr[f] = f2bf(v);
    }
}

// ---------------------------------------------------------------------------
// MFMA bf16 GEMM: C[m,n] = sum_k A[m,k]*Bt[n,k], 128x128 tile, BK=32,
// 4 waves of 64x64, 16x16x32 MFMA. K must be mult of 32; staging unguarded
// (B-side arrays zero-padded to 128-mult rows; A-side overruns land in ws).
// LDS layout [k8][row] (slot = k8*128 + row, 16B slots): frag ds_read_b128
// is 2-way bank aliased (free).
// Epilogue modes:
//  0: reduc_bf[m*416+n] = bf(acc+bias[n]), n<416
//  1: hidden: n<600 -> hid4[(n/150)*NROW + m][n%150] = bf(relu(acc+bias[n]));
//     n in [600,640) -> zero pad cols 150..159 of each of the 4 arrays
//  2: affine: n<600 -> aff[((m/200)*800 + (m%200)*4 + n/150)*160 + n%150]
//     = bf(acc+bias[n]); n in [600,640) -> zero pads
//  3: outF[m*ldc+n] = acc  (m<M, n<Nv)
// ---------------------------------------------------------------------------
__global__ __launch_bounds__(256) void gemm_mfma(
    const short* __restrict__ A, long long sAb, int lda,
    const short* __restrict__ Bt, long long sBb, int ldb,
    const float* __restrict__ bias,
    short* __restrict__ outB, float* __restrict__ outF, long long sCb, int ldc,
    int M, int Nv, int K, int mode)
{
    __shared__ __align__(16) short AB[8192];   // A: 0..4095, B: 4096..8191

    int bz = blockIdx.z;
    A += (long long)bz * sAb;
    Bt += (long long)bz * sBb;

    int row0 = blockIdx.y * 128;
    int col0 = blockIdx.x * 128;
    int tid = threadIdx.x;
    int lane = tid & 63;
    int wv = tid >> 6;
    int wr = wv >> 1, wc = wv & 1;
    int lm = lane & 15, lk = lane >> 4;

    // staging slots (2 for A, 2 for B per thread)
    int s0 = tid, s1 = tid + 256;
    int am0 = s0 & 127, ak0 = s0 >> 7;
    int am1 = s1 & 127, ak1 = s1 >> 7;
    const short* gA0 = A + (long)(row0 + am0) * lda + ak0 * 8;
    const short* gA1 = A + (long)(row0 + am1) * lda + ak1 * 8;
    const short* gB0 = Bt + (long)(col0 + am0) * ldb + ak0 * 8;
    const short* gB1 = Bt + (long)(col0 + am1) * ldb + ak1 * 8;
    short* lA0 = &AB[s0 * 8];
    short* lA1 = &AB[s1 * 8];
    short* lB0 = &AB[4096 + s0 * 8];
    short* lB1 = &AB[4096 + s1 * 8];

    // fragment read bases
    const short* fA = &AB[(lk * 128 + wr * 64 + lm) * 8];
    const short* fB = &AB[4096 + (lk * 128 + wc * 64 + lm) * 8];

    floatx4 acc[4][4];
#pragma unroll
    for (int i = 0; i < 4; ++i)
#pragma unroll
        for (int j = 0; j < 4; ++j)
            acc[i][j] = (floatx4){0.f, 0.f, 0.f, 0.f};

    for (int k0 = 0; k0 < K; k0 += 32) {
        gload16(gA0 + k0, lA0);
        gload16(gA1 + k0, lA1);
        gload16(gB0 + k0, lB0);
        gload16(gB1 + k0, lB1);
        __syncthreads();
        short8 a[4], b[4];
#pragma unroll
        for (int mt = 0; mt < 4; ++mt) a[mt] = *(const short8*)(fA + mt * 128);
#pragma unroll
        for (int nt = 0; nt < 4; ++nt) b[nt] = *(const short8*)(fB + nt * 128);
#pragma unroll
        for (int mt = 0; mt < 4; ++mt)
#pragma unroll
            for (int nt = 0; nt < 4; ++nt)
                acc[mt][nt] = __builtin_amdgcn_mfma_f32_16x16x32_bf16(
                    a[mt], b[nt], acc[mt][nt], 0, 0, 0);
        __syncthreads();
    }

    // epilogue
#pragma unroll
    for (int mt = 0; mt < 4; ++mt) {
#pragma unroll
        for (int nt = 0; nt < 4; ++nt) {
#pragma unroll
            for (int r = 0; r < 4; ++r) {
                int gm = row0 + wr * 64 + mt * 16 + (lane >> 4) * 4 + r;
                int gn = col0 + wc * 64 + nt * 16 + (lane & 15);
                float v = acc[mt][nt][r];
                if (mode == 0) {
                    if (gn < Nv)
                        outB[(long)gm * ldc + gn] = f2bf(v + bias[gn]);
                } else if (mode == 1) {
                    if (gn < 600) {
                        v = fmaxf(v + bias[gn], 0.0f);
                        outB[((long)(gn / 150) * NROW + gm) * KD + gn % 150] = f2bf(v);
                    } else if (gn < 640) {
                        int q = gn - 600;
                        outB[((long)(q / 10) * NROW + gm) * KD + 150 + q % 10] = 0;
                    }
                } else if (mode == 2) {
                    int bb = gm / 200, l = gm % 200;
                    if (gn < 600) {
                        v += bias[gn];
                        outB[((long)bb * 800 + l * 4 + gn / 150) * KD + gn % 150] = f2bf(v);
                    } else if (gn < 640) {
                        int q = gn - 600;
                        outB[((long)bb * 800 + l * 4 + q / 10) * KD + 150 + q % 10] = 0;
                    }
                } else {
                    if (gm < M && gn < Nv)
                        outF[(long long)bz * sCb + (long)gm * ldc + gn] = v;
                }
            }
        }
    }
}

// ---------------------------------------------------------------------------
// tags: per-row K=150 dots from bf16 ap_rep/op_rep (hid4[0], hid4[1])
// ---------------------------------------------------------------------------
__global__ __launch_bounds__(256) void tags_kernel(
    const short* __restrict__ hid4,
    const float* __restrict__ W_aptag, const float* __restrict__ b_aptag,
    const float* __restrict__ W_optag, const float* __restrict__ b_optag,
    float* __restrict__ out_ap, float* __restrict__ out_op)
{
    int wave = threadIdx.x / 64;
    int lane = threadIdx.x % 64;
    int row = blockIdx.x * 4 + wave;
    if (row >= NROW) return;

#pragma unroll
    for (int which = 0; which < 2; ++which) {
        const short* rep = hid4 + ((long)which * NROW + row) * KD;
        const float* W = which ? W_optag : W_aptag;
        const float* bb = which ? b_optag : b_aptag;
        float* out = which ? out_op : out_ap;
        float v0 = bf2f(rep[lane]);
        float v1 = bf2f(rep[64 + lane]);
        float v2 = (lane < 22) ? bf2f(rep[128 + lane]) : 0.0f;
#pragma unroll
        for (int t = 0; t < TAGS; ++t) {
            const float* w = W + t * 150;
            float p = v0 * w[lane] + v1 * w[64 + lane] +
                      ((lane < 22) ? v2 * w[128 + lane] : 0.0f);
#pragma unroll
            for (int off = 32; off > 0; off >>= 1) p += __shfl_down(p, off);
            if (lane == 0) out[row * TAGS + t] = p + bb[t];
        }
    }
}

// ---------------------------------------------------------------------------
extern "C" void kernel_launch(void* const* d_in, const int* in_sizes, int n_in,
                              void* d_out, int out_size, void* d_ws, size_t ws_size,
                              hipStream_t stream)
{
    const float* bert      = (const float*)d_in[0];
    const int*   positions = (const int*)d_in[1];
    const int*   postag    = (const int*)d_in[2];
    const float* embed     = (const float*)d_in[3];
    const float* W_reduc   = (const float*)d_in[4];
    const float* b_reduc   = (const float*)d_in[5];
    const float* W_ap      = (const float*)d_in[6];
    const float* b_ap      = (const float*)d_in[7];
    const float* W_op      = (const float*)d_in[8];
    const float* b_op      = (const float*)d_in[9];
    const float* W_ap2     = (const float*)d_in[10];
    const float* b_ap2     = (const float*)d_in[11];
    const float* W_op2     = (const float*)d_in[12];
    const float* b_op2     = (const float*)d_in[13];
    const float* W_aptag   = (const float*)d_in[14];
    const float* b_aptag   = (const float*)d_in[15];
    const float* W_optag   = (const float*)d_in[16];
    const float* b_optag   = (const float*)d_in[17];
    const float* W_bi      = (const float*)d_in[18];

    float* out = (float*)d_out;
    float* out_ap  = out;                       // [25600,5]
    float* out_op  = out + NROW * TAGS;         // [25600,5]
    float* out_tri = out + 2 * NROW * TAGS;     // [128,200,800]

    // workspace layout (shorts, all offsets 64B-aligned)
    short* ws = (short*)d_ws;
    short* h_bf     = ws;                               // 25600*832 = 21,299,200
    short* affine   = h_bf;                             // alias (h dead after GEMM1; 16,384,000 fits)
    short* reduc_bf = h_bf + (long)NROW * KH;           // 25600*416 = 10,649,600
    short* hid4     = reduc_bf + (long)NROW * KR;       // 4*25600*160 = 16,384,000
    short* Wr_bf    = hid4 + (long)4 * NROW * KD;       // 512*832 = 425,984
    short* Wh_bf    = Wr_bf + 512 * KH;                 // 640*416 = 266,240
    short* Wbi_bf   = Wh_bf + 640 * KR;                 // 640*160 = 102,400
    float* br_pad   = (float*)(Wbi_bf + 640 * KD);      // 416
    float* bh_pad   = br_pad + KR;                      // 640
    float* bbi_pad  = bh_pad + 640;                     // 640

    // 1. weight prep
    prep_kernel<<<(512 * KH + 255) / 256, 256, 0, stream>>>(
        W_reduc, W_ap, W_op, W_ap2, W_op2, W_bi,
        b_reduc, b_ap, b_op, b_ap2, b_op2,
        Wr_bf, Wh_bf, Wbi_bf, br_pad, bh_pad, bbi_pad);

    // 2. pool -> h_bf [25600][832]
    pool_kernel<<<NROW, 256, 0, stream>>>(bert, positions, postag, embed, h_bf);

    // 3. reduc_bf = bf(h @ Wr^T + br)  M=25600 N=416 K=832
    {
        dim3 g(4, NROW / 128, 1);
        gemm_mfma<<<g, 256, 0, stream>>>(h_bf, 0, KH, Wr_bf, 0, KH, br_pad,
                                         reduc_bf, nullptr, 0, KR,
                                         NROW, KR, KH, 0);
    }
    // 4. hid4 = relu(reduc @ Wh^T + bh) -> 4x [25600][160] bf16 (pads zeroed)
    {
        dim3 g(5, NROW / 128, 1);
        gemm_mfma<<<g, 256, 0, stream>>>(reduc_bf, 0, KR, Wh_bf, 0, KR, bh_pad,
                                         hid4, nullptr, 0, 0,
                                         NROW, 600, KR, 1);
    }
    // 5. tag heads
    tags_kernel<<<NROW / 4, 256, 0, stream>>>(hid4, W_aptag, b_aptag,
                                              W_optag, b_optag, out_ap, out_op);
    // 6. affine = ap_node @ Wbi^T + bbi -> scattered [128][800][160] bf16
    {
        dim3 g(5, NROW / 128, 1);
        gemm_mfma<<<g, 256, 0, stream>>>(hid4 + (long)2 * NROW * KD, 0, KD,
                                         Wbi_bf, 0, KD, bbi_pad,
                                         affine, nullptr, 0, 0,
                                         NROW, 600, KD, 2);
    }
    // 7. tri: per batch, C[l2][k] = op_node[l2,:]·affine[k,:]  M=200 N=800 K=160
    {
        dim3 g(7, 2, Bsz);
        gemm_mfma<<<g, 256, 0, stream>>>(hid4 + (long)3 * NROW * KD, (long long)200 * KD, KD,
                                         affine, (long long)800 * KD, KD, nullptr,
                                         nullptr, out_tri, (long long)200 * 800, 800,
                                         200, 800, KD, 3);
    }
}

// Round 3
// 469.770 us; speedup vs baseline: 2.4003x; 1.0931x over previous
//
#include <hip/hip_runtime.h>
#include <hip/hip_bf16.h>

// Problem constants
#define Bsz 128
#define Ssz 256
#define Lsz 200
#define Dsz 768
#define POS_DIM 50
#define TAGS 5
#define NROW 25600          // B*L
#define FIN 818             // D + POS_DIM
#define KH 832              // FIN padded to mult of 32
#define KR 416              // REDUC=400 padded
#define KD 160              // HID=150 padded

typedef __attribute__((ext_vector_type(8))) short short8;
typedef __attribute__((ext_vector_type(4))) short short4v;
typedef __attribute__((ext_vector_type(4))) float floatx4;

__device__ __forceinline__ short f2bf(float v) {
    __hip_bfloat16 h = __float2bfloat16(v);
    short s; __builtin_memcpy(&s, &h, 2); return s;
}
__device__ __forceinline__ float bf2f(short s) {
    __hip_bfloat16 h; __builtin_memcpy(&h, &s, 2);
    return __bfloat162float(h);
}

__device__ __forceinline__ void gload16(const short* g, short* l) {
    __builtin_amdgcn_global_load_lds(
        (const __attribute__((address_space(1))) void*)g,
        (__attribute__((address_space(3))) void*)l, 16, 0, 0);
}

// ---------------------------------------------------------------------------
// prep: zero-padded bf16 weights + padded fp32 biases.
// NOTE feature permutation for the reduc GEMM: k=0..767 <- bert dims,
// k=768..817 <- pos-emb dims, k=818..831 zero. Wr_bf permuted to match.
//   Wr_bf  [512][832], Wh_bf [640][416], Wbi_bf [640][160]
//   br_pad[416], bh_pad[640], bbi_pad[640] (= W_bi[:,150])
// ---------------------------------------------------------------------------
__global__ void prep_kernel(const float* __restrict__ W_reduc,
                            const float* __restrict__ W_ap, const float* __restrict__ W_op,
                            const float* __restrict__ W_ap2, const float* __restrict__ W_op2,
                            const float* __restrict__ W_bi,
                            const float* __restrict__ b_reduc,
                            const float* __restrict__ b_ap, const float* __restrict__ b_op,
                            const float* __restrict__ b_ap2, const float* __restrict__ b_op2,
                            short* __restrict__ Wr_bf, short* __restrict__ Wh_bf,
                            short* __restrict__ Wbi_bf,
                            float* __restrict__ br_pad, float* __restrict__ bh_pad,
                            float* __restrict__ bbi_pad)
{
    int i = blockIdx.x * blockDim.x + threadIdx.x;
    if (i < 512 * KH) {
        int r = i / KH, k = i % KH;
        float v = 0.0f;
        if (r < 400) {
            if (k < 768)       v = W_reduc[r * FIN + POS_DIM + k];   // bert dim k
            else if (k < 818)  v = W_reduc[r * FIN + (k - 768)];     // pos dim
        }
        Wr_bf[i] = f2bf(v);
    }
    if (i < 640 * KR) {
        int r = i / KR, c = i % KR;
        float v = 0.0f;
        if (r < 600 && c < 400) {
            const float* src = (r < 150) ? W_ap : (r < 300) ? W_op : (r < 450) ? W_ap2 : W_op2;
            v = src[(r % 150) * 400 + c];
        }
        Wh_bf[i] = f2bf(v);
    }
    if (i < 640 * KD) {
        int r = i / KD, c = i % KD;
        Wbi_bf[i] = (r < 600 && c < 150) ? f2bf(W_bi[r * 151 + c]) : (short)0;
    }
    if (i < KR) br_pad[i] = (i < 400) ? b_reduc[i] : 0.0f;
    if (i < 640) {
        float v = 0.0f;
        if (i < 600) {
            const float* bs = (i < 150) ? b_ap : (i < 300) ? b_op : (i < 450) ? b_ap2 : b_op2;
            v = bs[i % 150];
        }
        bh_pad[i] = v;
        bbi_pad[i] = (i < 600) ? W_bi[i * 151 + 150] : 0.0f;
    }
}

// ---------------------------------------------------------------------------
// pool (permuted layout): h_bf[row][0:768]=span-mean bert (float4 reads),
// [768:818]=embed[tag], [818:832]=0. One row per block, short4 writes.
// ---------------------------------------------------------------------------
__global__ __launch_bounds__(256) void pool_kernel(
    const float* __restrict__ bert,
    const int* __restrict__ positions,
    const int* __restrict__ postag,
    const float* __restrict__ embed,
    short* __restrict__ h_bf)
{
    int row = blockIdx.x;
    int b = row / Lsz;
    int st = positions[row * 2 + 0];
    int en = positions[row * 2 + 1];
    int tag = postag[row];
    int span = en - st + 1;
    float inv = 1.0f / (float)span;
    const float* base = bert + ((long)b * Ssz + st) * Dsz;
    short* hr = h_bf + (long)row * KH;

    int t = threadIdx.x;
    int c0 = t * 4;                    // 4 columns per thread; 256*4=1024 >= 832
    if (c0 >= KH) return;
    short4v o;
    if (c0 < 768) {
        float4 s = {0.f, 0.f, 0.f, 0.f};
        for (int i = 0; i < span; ++i) {
            float4 v = *(const float4*)(base + i * Dsz + c0);
            s.x += v.x; s.y += v.y; s.z += v.z; s.w += v.w;
        }
        o.x = f2bf(s.x * inv); o.y = f2bf(s.y * inv);
        o.z = f2bf(s.z * inv); o.w = f2bf(s.w * inv);
    } else {
        const float* e = embed + tag * POS_DIM;
#pragma unroll
        for (int j = 0; j < 4; ++j) {
            int c = c0 + j - 768;      // embed idx
            float v = (c < POS_DIM) ? e[c] : 0.0f;
            ((short*)&o)[j] = f2bf(v);
        }
    }
    *(short4v*)(hr + c0) = o;
}

// ---------------------------------------------------------------------------
// MFMA bf16 GEMM: C[m,n] = sum_k A[m,k]*Bt[n,k]. Tile 64(M)x128(N), BK=32,
// 4 waves: wave wv owns all 64 rows x cols [wv*32, wv*32+32) -> 4x2 mfma
// tiles of 16x16x32. Staging via global_load_lds width 16, no conditionals
// (K mult of 32; B rows padded; A overrun lands in finite ws data — those
// rows/cols are discarded by the epilogue guards).
// LDS: A slot = k8*64+row (2048 slots), B slot = k8*128+row (4096 slots).
// Epilogue modes:
//  0: outB[m*ldc+n] = bf(acc+bias[n]), n<Nv
//  1: hidden: n<600 -> hid4[(n/150)*NROW+m][n%150] = bf(relu(acc+bias[n]));
//     n in [600,640) -> zero pad cols
//  2: affine: n<600 -> aff[((m/200)*800+(m%200)*4+n/150)*160+n%150]
//     = bf(acc+bias[n]); n in [600,640) -> zero pads
//  3: outF[bz*sCb + m*ldc+n] = acc  (m<M, n<Nv)
// ---------------------------------------------------------------------------
__global__ __launch_bounds__(256) void gemm_mfma(
    const short* __restrict__ A, long long sAb, int lda,
    const short* __restrict__ Bt, long long sBb, int ldb,
    const float* __restrict__ bias,
    short* __restrict__ outB, float* __restrict__ outF, long long sCb, int ldc,
    int M, int Nv, int K, int mode)
{
    __shared__ __align__(16) short AB[6144];   // A: 0..2047, B: 2048..6143

    int bz = blockIdx.z;
    A += (long long)bz * sAb;
    Bt += (long long)bz * sBb;

    int row0 = blockIdx.y * 64;
    int col0 = blockIdx.x * 128;
    int tid = threadIdx.x;
    int lane = tid & 63;
    int wv = tid >> 6;
    int lm = lane & 15, lk = lane >> 4;

    // staging: A chunk t (256 chunks), B chunks t and t+256 (512 chunks)
    const short* gA0 = A + (long)(row0 + (tid & 63)) * lda + (tid >> 6) * 8;
    int bc0 = tid, bc1 = tid + 256;
    const short* gB0 = Bt + (long)(col0 + (bc0 & 127)) * ldb + (bc0 >> 7) * 8;
    const short* gB1 = Bt + (long)(col0 + (bc1 & 127)) * ldb + (bc1 >> 7) * 8;
    short* lA0 = &AB[tid * 8];
    short* lB0 = &AB[2048 + bc0 * 8];
    short* lB1 = &AB[2048 + bc1 * 8];

    // fragment read bases
    const short* fA = &AB[(lk * 64 + lm) * 8];                    // + mt*16*8
    const short* fB = &AB[2048 + (lk * 128 + wv * 32 + lm) * 8];  // + nt*16*8

    floatx4 acc[4][2];
#pragma unroll
    for (int i = 0; i < 4; ++i)
#pragma unroll
        for (int j = 0; j < 2; ++j)
            acc[i][j] = (floatx4){0.f, 0.f, 0.f, 0.f};

    for (int k0 = 0; k0 < K; k0 += 32) {
        gload16(gA0 + k0, lA0);
        gload16(gB0 + k0, lB0);
        gload16(gB1 + k0, lB1);
        __syncthreads();
        short8 a[4], b[2];
#pragma unroll
        for (int mt = 0; mt < 4; ++mt) a[mt] = *(const short8*)(fA + mt * 128);
#pragma unroll
        for (int nt = 0; nt < 2; ++nt) b[nt] = *(const short8*)(fB + nt * 128);
#pragma unroll
        for (int mt = 0; mt < 4; ++mt)
#pragma unroll
            for (int nt = 0; nt < 2; ++nt)
                acc[mt][nt] = __builtin_amdgcn_mfma_f32_16x16x32_bf16(
                    a[mt], b[nt], acc[mt][nt], 0, 0, 0);
        __syncthreads();
    }

    // epilogue
#pragma unroll
    for (int mt = 0; mt < 4; ++mt) {
#pragma unroll
        for (int nt = 0; nt < 2; ++nt) {
#pragma unroll
            for (int r = 0; r < 4; ++r) {
                int gm = row0 + mt * 16 + lk * 4 + r;
                int gn = col0 + wv * 32 + nt * 16 + lm;
                float v = acc[mt][nt][r];
                if (mode == 0) {
                    if (gn < Nv)
                        outB[(long)gm * ldc + gn] = f2bf(v + bias[gn]);
                } else if (mode == 1) {
                    if (gn < 600) {
                        v = fmaxf(v + bias[gn], 0.0f);
                        outB[((long)(gn / 150) * NROW + gm) * KD + gn % 150] = f2bf(v);
                    } else if (gn < 640) {
                        int q = gn - 600;
                        outB[((long)(q / 10) * NROW + gm) * KD + 150 + q % 10] = 0;
                    }
                } else if (mode == 2) {
                    int bb = gm / 200, l = gm % 200;
                    if (gn < 600) {
                        v += bias[gn];
                        outB[((long)bb * 800 + l * 4 + gn / 150) * KD + gn % 150] = f2bf(v);
                    } else if (gn < 640) {
                        int q = gn - 600;
                        outB[((long)bb * 800 + l * 4 + q / 10) * KD + 150 + q % 10] = 0;
                    }
                } else {
                    if (gm < M && gn < Nv)
                        outF[(long long)bz * sCb + (long)gm * ldc + gn] = v;
                }
            }
        }
    }
}

// ---------------------------------------------------------------------------
// tags: per-row K=150 dots from bf16 ap_rep/op_rep (hid4[0], hid4[1])
// ---------------------------------------------------------------------------
__global__ __launch_bounds__(256) void tags_kernel(
    const short* __restrict__ hid4,
    const float* __restrict__ W_aptag, const float* __restrict__ b_aptag,
    const float* __restrict__ W_optag, const float* __restrict__ b_optag,
    float* __restrict__ out_ap, float* __restrict__ out_op)
{
    int wave = threadIdx.x / 64;
    int lane = threadIdx.x % 64;
    int row = blockIdx.x * 4 + wave;
    if (row >= NROW) return;

#pragma unroll
    for (int which = 0; which < 2; ++which) {
        const short* rep = hid4 + ((long)which * NROW + row) * KD;
        const float* W = which ? W_optag : W_aptag;
        const float* bb = which ? b_optag : b_aptag;
        float* out = which ? out_op : out_ap;
        float v0 = bf2f(rep[lane]);
        float v1 = bf2f(rep[64 + lane]);
        float v2 = (lane < 22) ? bf2f(rep[128 + lane]) : 0.0f;
#pragma unroll
        for (int t = 0; t < TAGS; ++t) {
            const float* w = W + t * 150;
            float p = v0 * w[lane] + v1 * w[64 + lane] +
                      ((lane < 22) ? v2 * w[128 + lane] : 0.0f);
#pragma unroll
            for (int off = 32; off > 0; off >>= 1) p += __shfl_down(p, off);
            if (lane == 0) out[row * TAGS + t] = p + bb[t];
        }
    }
}

// ---------------------------------------------------------------------------
extern "C" void kernel_launch(void* const* d_in, const int* in_sizes, int n_in,
                              void* d_out, int out_size, void* d_ws, size_t ws_size,
                              hipStream_t stream)
{
    const float* bert      = (const float*)d_in[0];
    const int*   positions = (const int*)d_in[1];
    const int*   postag    = (const int*)d_in[2];
    const float* embed     = (const float*)d_in[3];
    const float* W_reduc   = (const float*)d_in[4];
    const float* b_reduc   = (const float*)d_in[5];
    const float* W_ap      = (const float*)d_in[6];
    const float* b_ap      = (const float*)d_in[7];
    const float* W_op      = (const float*)d_in[8];
    const float* b_op      = (const float*)d_in[9];
    const float* W_ap2     = (const float*)d_in[10];
    const float* b_ap2     = (const float*)d_in[11];
    const float* W_op2     = (const float*)d_in[12];
    const float* b_op2     = (const float*)d_in[13];
    const float* W_aptag   = (const float*)d_in[14];
    const float* b_aptag   = (const float*)d_in[15];
    const float* W_optag   = (const float*)d_in[16];
    const float* b_optag   = (const float*)d_in[17];
    const float* W_bi      = (const float*)d_in[18];

    float* out = (float*)d_out;
    float* out_ap  = out;                       // [25600,5]
    float* out_op  = out + NROW * TAGS;         // [25600,5]
    float* out_tri = out + 2 * NROW * TAGS;     // [128,200,800]

    // workspace layout (shorts)
    short* ws = (short*)d_ws;
    short* h_bf     = ws;                               // 25600*832 = 21,299,200
    short* affine   = h_bf;                             // alias (h dead after GEMM1)
    short* reduc_bf = h_bf + (long)NROW * KH;           // 25600*416
    short* hid4     = reduc_bf + (long)NROW * KR;       // 4*25600*160
    short* Wr_bf    = hid4 + (long)4 * NROW * KD;       // 512*832
    short* Wh_bf    = Wr_bf + 512 * KH;                 // 640*416
    short* Wbi_bf   = Wh_bf + 640 * KR;                 // 640*160
    float* br_pad   = (float*)(Wbi_bf + 640 * KD);      // 416
    float* bh_pad   = br_pad + KR;                      // 640
    float* bbi_pad  = bh_pad + 640;                     // 640

    // 1. weight prep
    prep_kernel<<<(512 * KH + 255) / 256, 256, 0, stream>>>(
        W_reduc, W_ap, W_op, W_ap2, W_op2, W_bi,
        b_reduc, b_ap, b_op, b_ap2, b_op2,
        Wr_bf, Wh_bf, Wbi_bf, br_pad, bh_pad, bbi_pad);

    // 2. pool -> h_bf [25600][832] (bert-first permuted layout)
    pool_kernel<<<NROW, 256, 0, stream>>>(bert, positions, postag, embed, h_bf);

    // 3. reduc_bf = bf(h @ Wr^T + br)  M=25600 N=416 K=832; grid 4x400=1600
    {
        dim3 g(4, NROW / 64, 1);
        gemm_mfma<<<g, 256, 0, stream>>>(h_bf, 0, KH, Wr_bf, 0, KH, br_pad,
                                         reduc_bf, nullptr, 0, KR,
                                         NROW, KR, KH, 0);
    }
    // 4. hid4 = relu(reduc @ Wh^T + bh); grid 5x400=2000
    {
        dim3 g(5, NROW / 64, 1);
        gemm_mfma<<<g, 256, 0, stream>>>(reduc_bf, 0, KR, Wh_bf, 0, KR, bh_pad,
                                         hid4, nullptr, 0, 0,
                                         NROW, 600, KR, 1);
    }
    // 5. tag heads
    tags_kernel<<<NROW / 4, 256, 0, stream>>>(hid4, W_aptag, b_aptag,
                                              W_optag, b_optag, out_ap, out_op);
    // 6. affine = ap_node @ Wbi^T + bbi -> scattered [128][800][160] bf16
    {
        dim3 g(5, NROW / 64, 1);
        gemm_mfma<<<g, 256, 0, stream>>>(hid4 + (long)2 * NROW * KD, 0, KD,
                                         Wbi_bf, 0, KD, bbi_pad,
                                         affine, nullptr, 0, 0,
                                         NROW, 600, KD, 2);
    }
    // 7. tri: per batch, C[l2][k] = op_node[l2,:]·affine[k,:]; grid 7x4x128
    {
        dim3 g(7, 4, Bsz);
        gemm_mfma<<<g, 256, 0, stream>>>(hid4 + (long)3 * NROW * KD, (long long)200 * KD, KD,
                                         affine, (long long)800 * KD, KD, nullptr,
                                         nullptr, out_tri, (long long)200 * 800, 800,
                                         200, 800, KD, 3);
    }
}